// Round 15
// baseline (100.554 us; speedup 1.0000x reference)
//
#include <hip/hip_runtime.h>
#include <hip/hip_bf16.h>

// Problem constants (from reference)
#define BATCH 512
#define NKER  256
#define LEN   1000      // embedding input length
#define EDIM  3
#define OUTN  128
#define NROWS (BATCH * NKER)      // 131072
#define NF4   (LEN / 4)           // 250 float4 per row
#define FC_IN (EDIM * NKER)       // 768

typedef float fv4 __attribute__((ext_vector_type(4)));

#define DOT4(a, w) ((a)[0]*(w)[0] + (a)[1]*(w)[1] + (a)[2]*(w)[2] + (a)[3]*(w)[3])

// ---------------- Stage 1: y[b,k,e] = sum_l x[b,k,l] * W_emb[e,l] ----------
// Round-13 proven core (pair of rows/iter, strided pairs, W in LDS read once
// per pair, NT loads, next-pair loads issued between DOT4s and the butterfly,
// full 6-chain butterfly, folded W_fc2 transpose, no min-waves cap) with ONE
// change: per-wave slab STAGGER — islab = (i + gw%8) % 8 — so concurrent
// waves spread across all 8 64MB slabs instead of hammering one in lockstep.
__global__ __launch_bounds__(256) void stage1_emb(const float* __restrict__ x,
                                                  const float* __restrict__ W_emb,
                                                  const float* __restrict__ W_fc2,
                                                  float* __restrict__ Wt,
                                                  float* __restrict__ y) {
    // Folded transpose: block b copies Wt[b*48 .. b*48+47] (2048*48 = 98304)
    if (threadIdx.x < 48) {
        const int t = blockIdx.x * 48 + threadIdx.x;
        const int j = t >> 7;          // 0..767
        const int o = t & (OUTN - 1);  // 0..127
        Wt[t] = W_fc2[o * FC_IN + j];
    }

    __shared__ float w_s[EDIM][LEN];   // 12 KB
    for (int i = threadIdx.x; i < EDIM * LEN; i += 256) {
        w_s[i / LEN][i % LEN] = W_emb[i];
    }
    __syncthreads();

    const int wave = threadIdx.x >> 6;
    const int lane = threadIdx.x & 63;
    const int gw = blockIdx.x * 4 + wave;           // global wave id, 0..8191
    const int ph = gw & 7;                          // slab phase offset

    const bool tail = (lane < NF4 - 192);           // lane < 58 has a 4th slice
    const int f3 = tail ? (lane + 192) : 0;         // clamped LDS index (x zeroed)
    const fv4 z4 = {0.f, 0.f, 0.f, 0.f};

    const fv4* w0p = reinterpret_cast<const fv4*>(&w_s[0][0]);
    const fv4* w1p = reinterpret_cast<const fv4*>(&w_s[1][0]);
    const fv4* w2p = reinterpret_cast<const fv4*>(&w_s[2][0]);

    // Prime: first pair's loads (slab (ph+0)&7 = ph)
    fv4 a0, a1, a2, a3, b0, b1, b2, b3;
    {
        const int r0 = gw * 2 + ph * 16384;
        const fv4* xa = reinterpret_cast<const fv4*>(x + (size_t)r0 * LEN);
        const fv4* xb = reinterpret_cast<const fv4*>(x + (size_t)(r0 + 1) * LEN);
        a0 = __builtin_nontemporal_load(&xa[lane]);
        a1 = __builtin_nontemporal_load(&xa[lane + 64]);
        a2 = __builtin_nontemporal_load(&xa[lane + 128]);
        a3 = tail ? __builtin_nontemporal_load(&xa[lane + 192]) : z4;
        b0 = __builtin_nontemporal_load(&xb[lane]);
        b1 = __builtin_nontemporal_load(&xb[lane + 64]);
        b2 = __builtin_nontemporal_load(&xb[lane + 128]);
        b3 = tail ? __builtin_nontemporal_load(&xb[lane + 192]) : z4;
    }

    #pragma unroll 1
    for (int i = 0; i < 8; ++i) {
        const int rowA = gw * 2 + (((i + ph) & 7) * 16384);   // staggered slab

        float sA0, sA1, sA2, sB0, sB1, sB2;
        {
            fv4 w;
            // chunk 0 (W read once, used for both rows)
            w = w0p[lane];       sA0  = DOT4(a0, w);  sB0  = DOT4(b0, w);
            w = w1p[lane];       sA1  = DOT4(a0, w);  sB1  = DOT4(b0, w);
            w = w2p[lane];       sA2  = DOT4(a0, w);  sB2  = DOT4(b0, w);
            // chunk 1
            w = w0p[lane + 64];  sA0 += DOT4(a1, w);  sB0 += DOT4(b1, w);
            w = w1p[lane + 64];  sA1 += DOT4(a1, w);  sB1 += DOT4(b1, w);
            w = w2p[lane + 64];  sA2 += DOT4(a1, w);  sB2 += DOT4(b1, w);
            // chunk 2
            w = w0p[lane + 128]; sA0 += DOT4(a2, w);  sB0 += DOT4(b2, w);
            w = w1p[lane + 128]; sA1 += DOT4(a2, w);  sB1 += DOT4(b2, w);
            w = w2p[lane + 128]; sA2 += DOT4(a2, w);  sB2 += DOT4(b2, w);
            // chunk 3 (tail; x zeroed for lanes >= 58, W index clamped)
            w = w0p[f3];         sA0 += DOT4(a3, w);  sB0 += DOT4(b3, w);
            w = w1p[f3];         sA1 += DOT4(a3, w);  sB1 += DOT4(b3, w);
            w = w2p[f3];         sA2 += DOT4(a3, w);  sB2 += DOT4(b3, w);
        }

        // Issue next pair's loads NOW (registers just went dead -> WAR reuse,
        // no added live set). The butterfly below runs with 8 loads in flight.
        if (i + 1 < 8) {    // uniform (scalar) branch
            const int rowN = gw * 2 + (((i + 1 + ph) & 7) * 16384);
            const fv4* xa = reinterpret_cast<const fv4*>(x + (size_t)rowN * LEN);
            const fv4* xb = reinterpret_cast<const fv4*>(x + (size_t)(rowN + 1) * LEN);
            a0 = __builtin_nontemporal_load(&xa[lane]);
            a1 = __builtin_nontemporal_load(&xa[lane + 64]);
            a2 = __builtin_nontemporal_load(&xa[lane + 128]);
            a3 = tail ? __builtin_nontemporal_load(&xa[lane + 192]) : z4;
            b0 = __builtin_nontemporal_load(&xb[lane]);
            b1 = __builtin_nontemporal_load(&xb[lane + 64]);
            b2 = __builtin_nontemporal_load(&xb[lane + 128]);
            b3 = tail ? __builtin_nontemporal_load(&xb[lane + 192]) : z4;
        }
        __builtin_amdgcn_sched_barrier(0);   // pin load issue above the reduce

        // Full 64-lane butterfly reduction: 6 independent chains (ILP)
        #pragma unroll
        for (int m = 32; m >= 1; m >>= 1) {
            sA0 += __shfl_xor(sA0, m);
            sA1 += __shfl_xor(sA1, m);
            sA2 += __shfl_xor(sA2, m);
            sB0 += __shfl_xor(sB0, m);
            sB1 += __shfl_xor(sB1, m);
            sB2 += __shfl_xor(sB2, m);
        }
        if (lane == 0) {
            float* yr = y + (size_t)rowA * EDIM;   // rows A,B contiguous: 24 B
            yr[0] = sA0;
            yr[1] = sA1;
            yr[2] = sA2;
            yr[3] = sB0;
            yr[4] = sB1;
            yr[5] = sB2;
        }
    }
}

// ---------------- Stage 2: out[b,o] = sum_j y[b,j] * Wt[j,o] + bias[o] ------
// Round-13 proven version: 256 blocks x 1024 threads, 2 rows/block,
// thread = (o, j-eighth), one Wt load feeds 2 FMAs.
__global__ __launch_bounds__(1024) void stage2_fc(const float* __restrict__ y,
                                                  const float* __restrict__ Wt,
                                                  const float* __restrict__ bias,
                                                  float* __restrict__ out) {
    __shared__ float ys[2][FC_IN];        // 6 KB
    __shared__ float part[2][7][OUTN];    // 7 KB
    const int b0 = blockIdx.x * 2;

    // Coalesced stage of both rows (contiguous 1536 floats = 384 fv4)
    const fv4* ysrc = reinterpret_cast<const fv4*>(y + (size_t)b0 * FC_IN);
    fv4* ydst = reinterpret_cast<fv4*>(&ys[0][0]);
    for (int i = threadIdx.x; i < 2 * FC_IN / 4; i += 1024) ydst[i] = ysrc[i];
    __syncthreads();

    const int o = threadIdx.x & (OUTN - 1);
    const int q = threadIdx.x >> 7;               // 0..7 (j-eighth)
    const int j0 = q * (FC_IN / 8);               // 96 iterations
    float acc0 = 0.f, acc1 = 0.f;
    #pragma unroll 8
    for (int j = j0; j < j0 + FC_IN / 8; ++j) {
        const float w = Wt[j * OUTN + o];   // coalesced; L2-hit; feeds 2 FMAs
        acc0 += ys[0][j] * w;
        acc1 += ys[1][j] * w;
    }
    if (q) {
        part[0][q - 1][o] = acc0;
        part[1][q - 1][o] = acc1;
    }
    __syncthreads();
    if (!q) {
        const float bo = bias[o];
        float s0 = acc0, s1 = acc1;
        #pragma unroll
        for (int p = 0; p < 7; ++p) {
            s0 += part[0][p][o];
            s1 += part[1][p][o];
        }
        out[(size_t)b0 * OUTN + o] = s0 + bo;
        out[(size_t)(b0 + 1) * OUTN + o] = s1 + bo;
    }
}

extern "C" void kernel_launch(void* const* d_in, const int* in_sizes, int n_in,
                              void* d_out, int out_size, void* d_ws, size_t ws_size,
                              hipStream_t stream) {
    const float* x     = (const float*)d_in[0];   // [512, 256, 1000]
    const float* W_emb = (const float*)d_in[1];   // [3, 1000]
    const float* W_fc2 = (const float*)d_in[2];   // [128, 768]
    const float* b_fc2 = (const float*)d_in[3];   // [128]
    float* out = (float*)d_out;                   // [512, 128]

    // Workspace layout: y [131072*3] floats, then Wt [768*128] floats
    float* y  = (float*)d_ws;
    float* Wt = y + (size_t)NROWS * EDIM;

    // Stage 1 (with folded W_fc2 transpose): 2048 blocks x 256 threads
    stage1_emb<<<2048, 256, 0, stream>>>(x, W_emb, W_fc2, Wt, y);

    // Stage 2: 256 blocks x 1024 threads (o x j-eighth x 2 rows)
    stage2_fc<<<BATCH / 2, 1024, 0, stream>>>(y, Wt, b_fc2, out);
}

// Round 16
// 95.672 us; speedup vs baseline: 1.0510x; 1.0510x over previous
//
#include <hip/hip_runtime.h>
#include <hip/hip_bf16.h>

// Problem constants (from reference)
#define BATCH 512
#define NKER  256
#define LEN   1000      // embedding input length
#define EDIM  3
#define OUTN  128
#define NROWS (BATCH * NKER)      // 131072
#define NF4   (LEN / 4)           // 250 float4 per row
#define FC_IN (EDIM * NKER)       // 768

typedef float fv4 __attribute__((ext_vector_type(4)));

#define DOT4(a, w) ((a)[0]*(w)[0] + (a)[1]*(w)[1] + (a)[2]*(w)[2] + (a)[3]*(w)[3])

// ---------------- Stage 1: y[b,k,e] = sum_l x[b,k,l] * W_emb[e,l] ----------
// Round-13 proven version (best: 95.7 us): pair of rows/iter, STRIDED pairs
// in lockstep slab order (beat consecutive R11 and staggered R14), W in LDS
// read once per pair, NT loads, next-pair loads issued between DOT4s and the
// butterfly (WAR reuse), full 6-chain butterfly, no min-waves cap, W_fc2
// transpose folded into the prologue.
__global__ __launch_bounds__(256) void stage1_emb(const float* __restrict__ x,
                                                  const float* __restrict__ W_emb,
                                                  const float* __restrict__ W_fc2,
                                                  float* __restrict__ Wt,
                                                  float* __restrict__ y) {
    // Folded transpose: block b copies Wt[b*48 .. b*48+47] (2048*48 = 98304)
    if (threadIdx.x < 48) {
        const int t = blockIdx.x * 48 + threadIdx.x;
        const int j = t >> 7;          // 0..767
        const int o = t & (OUTN - 1);  // 0..127
        Wt[t] = W_fc2[o * FC_IN + j];
    }

    __shared__ float w_s[EDIM][LEN];   // 12 KB
    for (int i = threadIdx.x; i < EDIM * LEN; i += 256) {
        w_s[i / LEN][i % LEN] = W_emb[i];
    }
    __syncthreads();

    const int wave = threadIdx.x >> 6;
    const int lane = threadIdx.x & 63;
    const int gw = blockIdx.x * 4 + wave;           // global wave id, 0..8191

    const bool tail = (lane < NF4 - 192);           // lane < 58 has a 4th slice
    const int f3 = tail ? (lane + 192) : 0;         // clamped LDS index (x zeroed)
    const fv4 z4 = {0.f, 0.f, 0.f, 0.f};

    const fv4* w0p = reinterpret_cast<const fv4*>(&w_s[0][0]);
    const fv4* w1p = reinterpret_cast<const fv4*>(&w_s[1][0]);
    const fv4* w2p = reinterpret_cast<const fv4*>(&w_s[2][0]);

    // Prime: first pair's loads
    fv4 a0, a1, a2, a3, b0, b1, b2, b3;
    {
        const fv4* xa = reinterpret_cast<const fv4*>(x + (size_t)(gw * 2) * LEN);
        const fv4* xb = reinterpret_cast<const fv4*>(x + (size_t)(gw * 2 + 1) * LEN);
        a0 = __builtin_nontemporal_load(&xa[lane]);
        a1 = __builtin_nontemporal_load(&xa[lane + 64]);
        a2 = __builtin_nontemporal_load(&xa[lane + 128]);
        a3 = tail ? __builtin_nontemporal_load(&xa[lane + 192]) : z4;
        b0 = __builtin_nontemporal_load(&xb[lane]);
        b1 = __builtin_nontemporal_load(&xb[lane + 64]);
        b2 = __builtin_nontemporal_load(&xb[lane + 128]);
        b3 = tail ? __builtin_nontemporal_load(&xb[lane + 192]) : z4;
    }

    #pragma unroll 1
    for (int i = 0; i < 8; ++i) {
        const int rowA = gw * 2 + i * 16384;        // pairs strided across array

        float sA0, sA1, sA2, sB0, sB1, sB2;
        {
            fv4 w;
            // chunk 0 (W read once, used for both rows)
            w = w0p[lane];       sA0  = DOT4(a0, w);  sB0  = DOT4(b0, w);
            w = w1p[lane];       sA1  = DOT4(a0, w);  sB1  = DOT4(b0, w);
            w = w2p[lane];       sA2  = DOT4(a0, w);  sB2  = DOT4(b0, w);
            // chunk 1
            w = w0p[lane + 64];  sA0 += DOT4(a1, w);  sB0 += DOT4(b1, w);
            w = w1p[lane + 64];  sA1 += DOT4(a1, w);  sB1 += DOT4(b1, w);
            w = w2p[lane + 64];  sA2 += DOT4(a1, w);  sB2 += DOT4(b1, w);
            // chunk 2
            w = w0p[lane + 128]; sA0 += DOT4(a2, w);  sB0 += DOT4(b2, w);
            w = w1p[lane + 128]; sA1 += DOT4(a2, w);  sB1 += DOT4(b2, w);
            w = w2p[lane + 128]; sA2 += DOT4(a2, w);  sB2 += DOT4(b2, w);
            // chunk 3 (tail; x zeroed for lanes >= 58, W index clamped)
            w = w0p[f3];         sA0 += DOT4(a3, w);  sB0 += DOT4(b3, w);
            w = w1p[f3];         sA1 += DOT4(a3, w);  sB1 += DOT4(b3, w);
            w = w2p[f3];         sA2 += DOT4(a3, w);  sB2 += DOT4(b3, w);
        }

        // Issue next pair's loads NOW (registers just went dead -> WAR reuse,
        // no added live set). The butterfly below runs with 8 loads in flight.
        if (i + 1 < 8) {    // uniform (scalar) branch
            const int rowN = gw * 2 + (i + 1) * 16384;
            const fv4* xa = reinterpret_cast<const fv4*>(x + (size_t)rowN * LEN);
            const fv4* xb = reinterpret_cast<const fv4*>(x + (size_t)(rowN + 1) * LEN);
            a0 = __builtin_nontemporal_load(&xa[lane]);
            a1 = __builtin_nontemporal_load(&xa[lane + 64]);
            a2 = __builtin_nontemporal_load(&xa[lane + 128]);
            a3 = tail ? __builtin_nontemporal_load(&xa[lane + 192]) : z4;
            b0 = __builtin_nontemporal_load(&xb[lane]);
            b1 = __builtin_nontemporal_load(&xb[lane + 64]);
            b2 = __builtin_nontemporal_load(&xb[lane + 128]);
            b3 = tail ? __builtin_nontemporal_load(&xb[lane + 192]) : z4;
        }
        __builtin_amdgcn_sched_barrier(0);   // pin load issue above the reduce

        // Full 64-lane butterfly reduction: 6 independent chains (ILP)
        #pragma unroll
        for (int m = 32; m >= 1; m >>= 1) {
            sA0 += __shfl_xor(sA0, m);
            sA1 += __shfl_xor(sA1, m);
            sA2 += __shfl_xor(sA2, m);
            sB0 += __shfl_xor(sB0, m);
            sB1 += __shfl_xor(sB1, m);
            sB2 += __shfl_xor(sB2, m);
        }
        if (lane == 0) {
            float* yr = y + (size_t)rowA * EDIM;   // rows A,B contiguous: 24 B
            yr[0] = sA0;
            yr[1] = sA1;
            yr[2] = sA2;
            yr[3] = sB0;
            yr[4] = sB1;
            yr[5] = sB2;
        }
    }
}

// ---------------- Stage 2: out[b,o] = sum_j y[b,j] * Wt[j,o] + bias[o] ------
// Round-13 proven version: 256 blocks x 1024 threads, 2 rows/block,
// thread = (o, j-eighth), one Wt load feeds 2 FMAs.
__global__ __launch_bounds__(1024) void stage2_fc(const float* __restrict__ y,
                                                  const float* __restrict__ Wt,
                                                  const float* __restrict__ bias,
                                                  float* __restrict__ out) {
    __shared__ float ys[2][FC_IN];        // 6 KB
    __shared__ float part[2][7][OUTN];    // 7 KB
    const int b0 = blockIdx.x * 2;

    // Coalesced stage of both rows (contiguous 1536 floats = 384 fv4)
    const fv4* ysrc = reinterpret_cast<const fv4*>(y + (size_t)b0 * FC_IN);
    fv4* ydst = reinterpret_cast<fv4*>(&ys[0][0]);
    for (int i = threadIdx.x; i < 2 * FC_IN / 4; i += 1024) ydst[i] = ysrc[i];
    __syncthreads();

    const int o = threadIdx.x & (OUTN - 1);
    const int q = threadIdx.x >> 7;               // 0..7 (j-eighth)
    const int j0 = q * (FC_IN / 8);               // 96 iterations
    float acc0 = 0.f, acc1 = 0.f;
    #pragma unroll 8
    for (int j = j0; j < j0 + FC_IN / 8; ++j) {
        const float w = Wt[j * OUTN + o];   // coalesced; L2-hit; feeds 2 FMAs
        acc0 += ys[0][j] * w;
        acc1 += ys[1][j] * w;
    }
    if (q) {
        part[0][q - 1][o] = acc0;
        part[1][q - 1][o] = acc1;
    }
    __syncthreads();
    if (!q) {
        const float bo = bias[o];
        float s0 = acc0, s1 = acc1;
        #pragma unroll
        for (int p = 0; p < 7; ++p) {
            s0 += part[0][p][o];
            s1 += part[1][p][o];
        }
        out[(size_t)b0 * OUTN + o] = s0 + bo;
        out[(size_t)(b0 + 1) * OUTN + o] = s1 + bo;
    }
}

extern "C" void kernel_launch(void* const* d_in, const int* in_sizes, int n_in,
                              void* d_out, int out_size, void* d_ws, size_t ws_size,
                              hipStream_t stream) {
    const float* x     = (const float*)d_in[0];   // [512, 256, 1000]
    const float* W_emb = (const float*)d_in[1];   // [3, 1000]
    const float* W_fc2 = (const float*)d_in[2];   // [128, 768]
    const float* b_fc2 = (const float*)d_in[3];   // [128]
    float* out = (float*)d_out;                   // [512, 128]

    // Workspace layout: y [131072*3] floats, then Wt [768*128] floats
    float* y  = (float*)d_ws;
    float* Wt = y + (size_t)NROWS * EDIM;

    // Stage 1 (with folded W_fc2 transpose): 2048 blocks x 256 threads
    stage1_emb<<<2048, 256, 0, stream>>>(x, W_emb, W_fc2, Wt, y);

    // Stage 2: 256 blocks x 1024 threads (o x j-eighth x 2 rows)
    stage2_fc<<<BATCH / 2, 1024, 0, stream>>>(y, Wt, b_fc2, out);
}